// Round 8
// baseline (376.021 us; speedup 1.0000x reference)
//
#include <hip/hip_runtime.h>
#include <hip/hip_bf16.h>

// Problem shapes (fixed):
//   hidden_states fp32 [WORLD=8][SEQ=2048][HID=4096]
//   gate_proj     fp32 [OUTD=8192][HID=4096]
//   out           fp32 [SEQ=2048][OUTD=8192]
// out = (sum_w hs[w]) @ W^T   (reduce-scatter sum commutes into the GEMM)

#define HID   4096
#define SEQ   2048
#define WORLD 8
#define OUTD  8192

typedef __bf16 bf16x8 __attribute__((ext_vector_type(8)));
typedef short  s16x8  __attribute__((ext_vector_type(8)));
typedef float  f32x4  __attribute__((ext_vector_type(4)));

typedef const __attribute__((address_space(1))) void* gas1_ptr;
typedef __attribute__((address_space(3))) void*       las3_ptr;

static __device__ __forceinline__ unsigned short f2bf(float f) {
    union { float f; unsigned u; } v; v.f = f;
    unsigned u = v.u;
    u += 0x7fffu + ((u >> 16) & 1u);   // round-to-nearest-even
    return (unsigned short)(u >> 16);
}

// ------------- Kernel 1: fused (reduce over world + cast) | (cast W) -------------
#define RED_BLOCKS  2048
#define CONV_BLOCKS 4096
__global__ void prep_kernel(const float* __restrict__ hs,
                            const float* __restrict__ w,
                            unsigned short* __restrict__ xb,
                            unsigned short* __restrict__ wb) {
    if (blockIdx.x < RED_BLOCKS) {
        const int total4 = SEQ * HID / 4;
        const float4* h4 = (const float4*)hs;
        ushort4* o4 = (ushort4*)xb;
        for (int i = blockIdx.x * blockDim.x + threadIdx.x; i < total4;
             i += RED_BLOCKS * blockDim.x) {
            float4 s = h4[i];
            #pragma unroll
            for (int ww = 1; ww < WORLD; ++ww) {
                float4 t = h4[i + ww * total4];
                s.x += t.x; s.y += t.y; s.z += t.z; s.w += t.w;
            }
            ushort4 o;
            o.x = f2bf(s.x); o.y = f2bf(s.y); o.z = f2bf(s.z); o.w = f2bf(s.w);
            o4[i] = o;
        }
    } else {
        const int total4 = OUTD * HID / 4;
        const float4* w4 = (const float4*)w;
        ushort4* o4 = (ushort4*)wb;
        for (int i = (blockIdx.x - RED_BLOCKS) * blockDim.x + threadIdx.x;
             i < total4; i += CONV_BLOCKS * blockDim.x) {
            float4 s = w4[i];
            ushort4 o;
            o.x = f2bf(s.x); o.y = f2bf(s.y); o.z = f2bf(s.z); o.w = f2bf(s.w);
            o4[i] = o;
        }
    }
}

// ---- Kernel 2: 128x128 bf16 GEMM C = A*B^T, A-in-LDS + B-direct-from-global ----
// 4 waves (2Mx2N), 64x64 out/wave. LDS = A ONLY, dbuf [2][128][64] bf16 = 32 KiB
// -> 3 blocks/CU (launch_bounds(256,3)): independent barrier groups per CU give
// cross-block MFMA/LDS overlap (m114) that single-block 256^2 schedules never
// achieved (r4-r7 all serial at ~950 TF).
// B is loaded global->VGPR (8 x b128/wave/K-tile, 16B/lane K-contiguous; the
// 8 KB wave panel is L1-resident), prefetched ONE K-TILE AHEAD. No B staging:
// halves LDS write traffic and removes 1/3 of LDS reads.
// Per K-tile: [barrier; STG_A(t+1) x4; A-reads x8; MFMA x32 (compiler lgkm);
//             load B(t+1) x8; vmcnt(8)] -- issue order [STG(4),B(8)] pinned by
// sched_barrier so vmcnt(8) certifies STG_A completion. Never vmcnt(0) in loop.
// Swizzle: 16B slot' = slot ^ (row&7) on pre-swizzled global source + ds_read.

#define BM 128
#define BN 128
#define BK 64
#define KSTEPS (HID / BK)   // 64

__global__ __launch_bounds__(256, 3)
void gemm_bt_kernel(const unsigned short* __restrict__ A,
                    const unsigned short* __restrict__ B,
                    float* __restrict__ C) {
    __shared__ __align__(16) unsigned short lsA[2][BM * BK];   // 32 KiB

    const int tid  = threadIdx.x;
    const int lane = tid & 63;
    const int wave = tid >> 6;      // 0..3
    const int wm   = wave >> 1;     // 0..1 -> rows wm*64
    const int wn   = wave & 1;      // 0..1 -> cols wn*64

    // 2D XCD tiling over (16 bm x 64 bn): 8 XCDs as 2x4; each XCD owns 8bm x 16bn.
    const int bid   = blockIdx.x;
    const int xcd   = bid & 7;
    const int local = bid >> 3;                     // 0..127
    const int bm = (xcd >> 2) * 8 + (local >> 4);   // 0..15
    const int bn = (xcd & 3) * 16 + (local & 15);   // 0..63

    // ---- A staging geometry: lane -> (subrow = lane>>3, slot = lane&7) ----
    // load l (0..3) covers rows [l*32 + wave*8, +8); (row & 7) == subrow
    const int subrow = lane >> 3;
    const int slot   = lane & 7;
    const int scol   = (slot ^ subrow) * 8;   // pre-swizzled global col (elems)
    const unsigned short* aBase =
        A + (size_t)(bm * BM + wave * 8 + subrow) * HID + scol;
    const int ldsW = wave * 8 * BK;           // wave-uniform LDS elem offset

#define ST_A(buf, ktv, l) __builtin_amdgcn_global_load_lds(                     \
        (gas1_ptr)(aBase + (size_t)(ktv) * BK + (size_t)(l) * 32 * HID),        \
        (las3_ptr)(&lsA[buf][(l) * 32 * BK + ldsW]), 16, 0, 0)
#define STG_A4(buf, ktv) do { ST_A(buf, ktv, 0); ST_A(buf, ktv, 1);             \
                              ST_A(buf, ktv, 2); ST_A(buf, ktv, 3); } while (0)

    // ---- fragment geometry ----
    const int fr    = lane & 15;
    const int fq    = lane >> 4;
    const int axor  = fr & 7;                  // (row & 7) for fragment rows
    const int koff0 = ((0 + fq) ^ axor) * 8;   // k-slice s=0
    const int koff1 = ((4 + fq) ^ axor) * 8;   // k-slice s=1
    const int aRowB = (wm * 64 + fr) * BK;

#define RD_A(dst, P, mm, koff) dst = __builtin_bit_cast(bf16x8,                 \
        *(const s16x8*)&lsA[P][aRowB + (mm) * 16 * BK + (koff)])

    // ---- B global per-lane bases (element units), one per n-frag ----
    // frag(n,s) of tile t: B[(bn*128 + wn*64 + n*16 + fr)][t*64 + (s*4+fq)*8 ..+8]
    const unsigned short* b0 =
        B + (size_t)(bn * BN + wn * 64 + fr) * HID + fq * 8;
    const unsigned short* b1 = b0 + (size_t)16 * HID;
    const unsigned short* b2 = b0 + (size_t)32 * HID;
    const unsigned short* b3 = b0 + (size_t)48 * HID;

#define BC8(p) __builtin_bit_cast(bf16x8, *(const s16x8*)(p))
#define LOADB() do {                                                            \
    vb[0][0] = BC8(b0); vb[0][1] = BC8(b0 + 32);                                \
    vb[1][0] = BC8(b1); vb[1][1] = BC8(b1 + 32);                                \
    vb[2][0] = BC8(b2); vb[2][1] = BC8(b2 + 32);                                \
    vb[3][0] = BC8(b3); vb[3][1] = BC8(b3 + 32);                                \
    b0 += BK; b1 += BK; b2 += BK; b3 += BK; } while (0)

#define BARRIER() __builtin_amdgcn_s_barrier()
#define VMC8()    asm volatile("s_waitcnt vmcnt(8)" ::: "memory")
#define PRIO1()   __builtin_amdgcn_s_setprio(1)
#define PRIO0()   __builtin_amdgcn_s_setprio(0)
#define SB()      __builtin_amdgcn_sched_barrier(0)

#define CLUSTER(m)                                                               \
    _Pragma("unroll")                                                            \
    for (int s = 0; s < 2; ++s)                                                  \
        _Pragma("unroll")                                                        \
        for (int n = 0; n < 4; ++n)                                              \
            acc[m][n] = __builtin_amdgcn_mfma_f32_16x16x32_bf16(                 \
                va[m][s], vb[n][s], acc[m][n], 0, 0, 0)

// One K-tile on buffer P (compile-time). HN = has-next (stage A(t+1), load B(t+1)).
// Entering: A(t) staged-certified (prev vmcnt8+barrier), B(t) in regs/in-flight
// (compiler inserts precise vmcnt waits before vb uses).
#define SECTION(P, TT, HN)                                                       \
    BARRIER(); SB();                                                             \
    if (HN) { STG_A4((P) ^ 1, (TT) + 1); }                                       \
    SB();                                                                        \
    RD_A(va[0][0], P, 0, koff0); RD_A(va[0][1], P, 0, koff1);                    \
    RD_A(va[1][0], P, 1, koff0); RD_A(va[1][1], P, 1, koff1);                    \
    RD_A(va[2][0], P, 2, koff0); RD_A(va[2][1], P, 2, koff1);                    \
    RD_A(va[3][0], P, 3, koff0); RD_A(va[3][1], P, 3, koff1);                    \
    PRIO1();                                                                     \
    CLUSTER(0); CLUSTER(1); CLUSTER(2); CLUSTER(3);                              \
    PRIO0(); SB();                                                               \
    if (HN) { LOADB(); }                                                         \
    SB();                                                                        \
    if (HN) { VMC8(); }                                                          \
    SB()

    f32x4 acc[4][4] = {};
    bf16x8 va[4][2], vb[4][2];

    // ---- prologue: stage A(0)->buf0; load B(0); certify A(0) (order pinned) ----
    STG_A4(0, 0);
    SB();
    LOADB();           // B(0); pointers now at tile 1
    SB();
    VMC8();            // [STG(4), B(8)]: <=8 -> A(0) staging retired
    SB();

    #pragma unroll 1
    for (int t = 0; t < KSTEPS; t += 2) {
        SECTION(0, t, true);                       // t+1 <= 63 always
        SECTION(1, t + 1, (t + 2 < KSTEPS));
    }

    // ---- epilogue: C/D layout col = lane&15, row = (lane>>4)*4 + j ----
    const long crow0 = (long)bm * BM + wm * 64 + fq * 4;
    const long ccol0 = (long)bn * BN + wn * 64 + fr;
    #pragma unroll
    for (int m = 0; m < 4; ++m)
        #pragma unroll
        for (int n = 0; n < 4; ++n)
            #pragma unroll
            for (int j = 0; j < 4; ++j)
                C[(crow0 + m * 16 + j) * OUTD + ccol0 + n * 16] = acc[m][n][j];
}

extern "C" void kernel_launch(void* const* d_in, const int* in_sizes, int n_in,
                              void* d_out, int out_size, void* d_ws, size_t ws_size,
                              hipStream_t stream) {
    const float* hs = (const float*)d_in[0];
    const float* w  = (const float*)d_in[1];
    float* out = (float*)d_out;

    unsigned short* xb = (unsigned short*)d_ws;              // 16 MB  [SEQ][HID] bf16
    unsigned short* wb = xb + (size_t)SEQ * HID;             // 64 MB  [OUTD][HID] bf16

    hipLaunchKernelGGL(prep_kernel, dim3(RED_BLOCKS + CONV_BLOCKS), dim3(256),
                       0, stream, hs, w, xb, wb);
    hipLaunchKernelGGL(gemm_bt_kernel, dim3((SEQ / BM) * (OUTD / BN)), dim3(256),
                       0, stream, xb, wb, out);
}

// Round 9
// 273.885 us; speedup vs baseline: 1.3729x; 1.3729x over previous
//
#include <hip/hip_runtime.h>
#include <hip/hip_bf16.h>

// Problem shapes (fixed):
//   hidden_states fp32 [WORLD=8][SEQ=2048][HID=4096]
//   gate_proj     fp32 [OUTD=8192][HID=4096]
//   out           fp32 [SEQ=2048][OUTD=8192]
// out = (sum_w hs[w]) @ W^T   (reduce-scatter sum commutes into the GEMM)
// W fp32->bf16 conversion is FUSED into the GEMM's B-staging (saves the
// 128MB read + 64MB write + 64MB re-read of the separate convert pass).

#define HID   4096
#define SEQ   2048
#define WORLD 8
#define OUTD  8192

typedef __bf16 bf16x8 __attribute__((ext_vector_type(8)));
typedef short  s16x8  __attribute__((ext_vector_type(8)));
typedef float  f32x4  __attribute__((ext_vector_type(4)));

typedef const __attribute__((address_space(1))) void* gas1_ptr;
typedef __attribute__((address_space(3))) void*       las3_ptr;

static __device__ __forceinline__ unsigned short f2bf(float f) {
    union { float f; unsigned u; } v; v.f = f;
    unsigned u = v.u;
    u += 0x7fffu + ((u >> 16) & 1u);   // round-to-nearest-even
    return (unsigned short)(u >> 16);
}

// pack two fp32 -> one u32 of 2 bf16 (round-half-up: err <= 2^-9 + 2^-25 bias)
static __device__ __forceinline__ unsigned pack_bf2(float a, float b) {
    unsigned ua = __builtin_bit_cast(unsigned, a) + 0x8000u;
    unsigned ub = __builtin_bit_cast(unsigned, b) + 0x8000u;
    return (ua >> 16) | (ub & 0xffff0000u);
}

// ------------- Kernel 1: reduce over world dim + cast to bf16 -------------
__global__ void reduce_x_kernel(const float* __restrict__ hs,
                                unsigned short* __restrict__ xb) {
    const int total4 = SEQ * HID / 4;
    const float4* h4 = (const float4*)hs;
    ushort4* o4 = (ushort4*)xb;
    for (int i = blockIdx.x * blockDim.x + threadIdx.x; i < total4;
         i += gridDim.x * blockDim.x) {
        float4 s = h4[i];
        #pragma unroll
        for (int w = 1; w < WORLD; ++w) {
            float4 t = h4[i + w * total4];
            s.x += t.x; s.y += t.y; s.z += t.z; s.w += t.w;
        }
        ushort4 o;
        o.x = f2bf(s.x); o.y = f2bf(s.y); o.z = f2bf(s.z); o.w = f2bf(s.w);
        o4[i] = o;
    }
}

// ---- Kernel 2: 256x256 bf16 GEMM C = A * W^T with fused W fp32->bf16 staging ----
// 8 waves (2Mx4N), 128x64 out/wave. LDS: A dbuf [2][256][64] via global_load_lds
// (pre-swizzled source), B dbuf [2][256][64] bf16 via reg-stage:
//   global fp32 (8 x b128/wave) -> pack_bf2 -> 4 x ds_write_b128 (swizzled dest).
// Swizzle both sides: 16B slot' = slot ^ (row&7).
// Per K-tile t (buf p, compile-time via 2x unroll), ONE barrier:
//   BARRIER                      // A(t),B(t) certified; buf q free
//   WRITE_B(q)  <- breg=B(t+1)   // compiler-counted vmcnt on breg
//   STG_A4(q, t+1)               // 4 global_load_lds
//   LOADB(t+2)  -> breg          // 8 global b128 fp32 (full tile in flight)
//   24 ds_reads + 64 MFMA (s,m-split; ~210 live VGPR)
//   LGKM0                        // drain ds_writes (+reads) before next barrier
//   VMC8                         // certify the 4 A-stages (older); leave 8 B-loads
// In-order vmcnt retire makes VMC8 exact. Never a false drain mid-loop.

#define BM 256
#define BN 256
#define BK 64
#define KSTEPS (HID / BK)   // 64

__global__ __launch_bounds__(512, 2)
void gemm_bt_kernel(const unsigned short* __restrict__ A,
                    const float* __restrict__ W,
                    float* __restrict__ C) {
    __shared__ __align__(16) unsigned short lsA[2][BM * BK];   // 64 KiB
    __shared__ __align__(16) unsigned short lsB[2][BN * BK];   // 64 KiB

    const int tid  = threadIdx.x;
    const int lane = tid & 63;
    const int wave = tid >> 6;
    const int wm   = wave >> 2;     // 0..1  -> rows wm*128
    const int wn   = wave & 3;      // 0..3  -> cols wn*64

    // 2D XCD tiling: xcd = bid&7 -> (gm,gn)=(xcd>>2, xcd&3); local 32 blocks = 4x8.
    const int bid   = blockIdx.x;
    const int xcd   = bid & 7;
    const int local = bid >> 3;               // 0..31
    const int bm = (xcd >> 2) * 4 + (local >> 3);   // 0..7
    const int bn = (xcd & 3) * 8 + (local & 7);     // 0..31

    // ---- A staging geometry: lane -> (subrow = lane>>3, slot = lane&7) ----
    const int subrow = lane >> 3;
    const int slot   = lane & 7;
    const int scol   = (slot ^ subrow) * 8;   // pre-swizzled global col (elems)
    const unsigned short* aBase =
        A + (size_t)(bm * BM + wave * 8 + subrow) * HID + scol;
    const int ldsW = wave * 8 * BK;           // wave-uniform LDS elem offset

#define ST_A(buf, ktv, l) __builtin_amdgcn_global_load_lds(                     \
        (gas1_ptr)(aBase + (size_t)(ktv) * BK + (size_t)(l) * 64 * HID),        \
        (las3_ptr)(&lsA[buf][(l) * 64 * BK + ldsW]), 16, 0, 0)
#define STG_A4(buf, ktv) do { ST_A(buf, ktv, 0); ST_A(buf, ktv, 1);             \
                              ST_A(buf, ktv, 2); ST_A(buf, ktv, 3); } while (0)

    // ---- B reg-staging geometry: lane -> row = wave*32 + (lane>>1), half = lane&1 ----
    // lane loads 32 contiguous fp32 (8 x b128) of its row per K-tile, packs to
    // 32 bf16, writes 4 x ds_write_b128 at swizzled slots.
    const int wrow = wave * 32 + (lane >> 1);        // 0..255
    const int wxor = (lane >> 1) & 7;                // wrow & 7
    const float* wBase =
        W + (size_t)(bn * BN + wrow) * HID + (lane & 1) * 32;

#define LOADB(T) do { _Pragma("unroll")                                         \
    for (int j = 0; j < 8; ++j)                                                 \
        breg[j] = *(const f32x4*)(wBase + (size_t)(T) * BK + j * 4); } while (0)

#define WRITE_B(Q) do { _Pragma("unroll")                                       \
    for (int j = 0; j < 4; ++j) {                                               \
        int4 wv;                                                                \
        wv.x = (int)pack_bf2(breg[2*j].x,   breg[2*j].y);                       \
        wv.y = (int)pack_bf2(breg[2*j].z,   breg[2*j].w);                       \
        wv.z = (int)pack_bf2(breg[2*j+1].x, breg[2*j+1].y);                     \
        wv.w = (int)pack_bf2(breg[2*j+1].z, breg[2*j+1].w);                     \
        *(int4*)&lsB[Q][wrow * BK +                                             \
            (((((lane & 1) * 4) + j) ^ wxor) * 8)] = wv;                        \
    } } while (0)

    // ---- fragment geometry ----
    const int fr    = lane & 15;
    const int fq    = lane >> 4;
    const int axor  = fr & 7;                  // (row & 7) for fragment rows
    const int koff0 = ((0 + fq) ^ axor) * 8;   // k-slice s=0
    const int koff1 = ((4 + fq) ^ axor) * 8;   // k-slice s=1
    const int aRowB = (wm * 128 + fr) * BK;
    const int bRowB = (wn * 64 + fr) * BK;

#define RD_A(dst, P, mm, koff) dst = __builtin_bit_cast(bf16x8,                 \
        *(const s16x8*)&lsA[P][aRowB + (mm) * 16 * BK + (koff)])
#define RD_B(dst, P, nn, koff) dst = __builtin_bit_cast(bf16x8,                 \
        *(const s16x8*)&lsB[P][bRowB + (nn) * 16 * BK + (koff)])

#define BARRIER() __builtin_amdgcn_s_barrier()
#define LGKM0()   asm volatile("s_waitcnt lgkmcnt(0)" ::: "memory")
#define VMC8()    asm volatile("s_waitcnt vmcnt(8)" ::: "memory")
#define VMC0()    asm volatile("s_waitcnt vmcnt(0)" ::: "memory")
#define PRIO1()   __builtin_amdgcn_s_setprio(1)
#define PRIO0()   __builtin_amdgcn_s_setprio(0)

// 8-MFMA cluster: m-pair (mb,mb+1) x n0-3, ONE k-slice, vb single-slice array
#define MFMA8(VA, mb)                                                            \
    PRIO1();                                                                     \
    _Pragma("unroll")                                                            \
    for (int m = 0; m < 2; ++m)                                                  \
        _Pragma("unroll")                                                        \
        for (int n = 0; n < 4; ++n)                                              \
            acc[(mb) + m][n] = __builtin_amdgcn_mfma_f32_16x16x32_bf16(          \
                VA[m], vb[n], acc[(mb) + m][n], 0, 0, 0);                        \
    PRIO0()

// One K-tile on buffer P. HAS1: tile T+1 exists; HAS2: tile T+2 exists.
#define TILE(P, T, HAS1, HAS2)                                                   \
    BARRIER();                                                                   \
    if (HAS1) { WRITE_B((P) ^ 1); STG_A4((P) ^ 1, (T) + 1); }                    \
    if (HAS2) { LOADB((T) + 2); }                                                \
    /* ---- k-slice s=0 ---- */                                                  \
    RD_B(vb[0], P, 0, koff0); RD_B(vb[1], P, 1, koff0);                          \
    RD_B(vb[2], P, 2, koff0); RD_B(vb[3], P, 3, koff0);                          \
    RD_A(va[0], P, 0, koff0); RD_A(va[1], P, 1, koff0);                          \
    MFMA8(va, 0);                                                                \
    RD_A(vc[0], P, 2, koff0); RD_A(vc[1], P, 3, koff0);                          \
    MFMA8(vc, 2);                                                                \
    RD_A(va[0], P, 4, koff0); RD_A(va[1], P, 5, koff0);                          \
    MFMA8(va, 4);                                                                \
    RD_A(vc[0], P, 6, koff0); RD_A(vc[1], P, 7, koff0);                          \
    MFMA8(vc, 6);                                                                \
    /* ---- k-slice s=1 ---- */                                                  \
    RD_B(vb[0], P, 0, koff1); RD_B(vb[1], P, 1, koff1);                          \
    RD_B(vb[2], P, 2, koff1); RD_B(vb[3], P, 3, koff1);                          \
    RD_A(va[0], P, 0, koff1); RD_A(va[1], P, 1, koff1);                          \
    MFMA8(va, 0);                                                                \
    RD_A(vc[0], P, 2, koff1); RD_A(vc[1], P, 3, koff1);                          \
    MFMA8(vc, 2);                                                                \
    RD_A(va[0], P, 4, koff1); RD_A(va[1], P, 5, koff1);                          \
    MFMA8(va, 4);                                                                \
    RD_A(vc[0], P, 6, koff1); RD_A(vc[1], P, 7, koff1);                          \
    LGKM0();                    /* drain ds_writes (+reads) before next barrier */\
    MFMA8(vc, 6);                                                                \
    if ((HAS1) && (HAS2)) { VMC8(); }      /* certify A-stage; B-loads in flight */\
    else if (HAS1)        { VMC0(); }      /* tail t=K-2: only the 4 stages left */

    f32x4 acc[8][4] = {};
    bf16x8 va[2], vc[2], vb[4];
    f32x4 breg[8];

    // ---- prologue: A(0)->buf0; B(0) reg->cvt->buf0; B(1)->reg; drain writes ----
    STG_A4(0, 0);
    LOADB(0);
    WRITE_B(0);        // compiler waits the B(0) loads (drains A(0) too: older)
    LOADB(1);          // 8 in flight entering the loop
    LGKM0();           // prologue ds_writes drained before tile0's barrier

    #pragma unroll 1
    for (int t = 0; t < KSTEPS; t += 2) {
        const bool g2 = (t + 2 < KSTEPS);
        const bool g3 = (t + 3 < KSTEPS);
        TILE(0, t,     true, g2);
        TILE(1, t + 1, g2,   g3);
    }

    // ---- epilogue: C/D layout col = lane&15, row = (lane>>4)*4 + j ----
    const long crow0 = (long)bm * BM + wm * 128 + fq * 4;
    const long ccol0 = (long)bn * BN + wn * 64 + fr;
    #pragma unroll
    for (int m = 0; m < 8; ++m)
        #pragma unroll
        for (int n = 0; n < 4; ++n)
            #pragma unroll
            for (int j = 0; j < 4; ++j)
                C[(crow0 + m * 16 + j) * OUTD + ccol0 + n * 16] = acc[m][n][j];
}

extern "C" void kernel_launch(void* const* d_in, const int* in_sizes, int n_in,
                              void* d_out, int out_size, void* d_ws, size_t ws_size,
                              hipStream_t stream) {
    const float* hs = (const float*)d_in[0];
    const float* w  = (const float*)d_in[1];
    float* out = (float*)d_out;

    unsigned short* xb = (unsigned short*)d_ws;      // 16 MB  [SEQ][HID] bf16

    hipLaunchKernelGGL(reduce_x_kernel, dim3(2048), dim3(256), 0, stream, hs, xb);
    hipLaunchKernelGGL(gemm_bt_kernel, dim3((SEQ / BM) * (OUTD / BN)), dim3(512),
                       0, stream, xb, w, out);
}

// Round 10
// 225.565 us; speedup vs baseline: 1.6670x; 1.2142x over previous
//
#include <hip/hip_runtime.h>
#include <hip/hip_bf16.h>

// Problem shapes (fixed):
//   hidden_states fp32 [WORLD=8][SEQ=2048][HID=4096]
//   gate_proj     fp32 [OUTD=8192][HID=4096]
//   out           fp32 [SEQ=2048][OUTD=8192]
// out = (sum_w hs[w]) @ W^T   (reduce-scatter sum commutes into the GEMM)

#define HID   4096
#define SEQ   2048
#define WORLD 8
#define OUTD  8192

typedef __bf16 bf16x8 __attribute__((ext_vector_type(8)));
typedef short  s16x8  __attribute__((ext_vector_type(8)));
typedef float  f32x4  __attribute__((ext_vector_type(4)));

typedef const __attribute__((address_space(1))) void* gas1_ptr;
typedef __attribute__((address_space(3))) void*       las3_ptr;

static __device__ __forceinline__ unsigned short f2bf(float f) {
    union { float f; unsigned u; } v; v.f = f;
    unsigned u = v.u;
    u += 0x7fffu + ((u >> 16) & 1u);   // round-to-nearest-even
    return (unsigned short)(u >> 16);
}

// ------------- Kernel 1: fused (reduce over world + cast) | (cast W) -------------
#define RED_BLOCKS  2048
#define CONV_BLOCKS 4096
__global__ void prep_kernel(const float* __restrict__ hs,
                            const float* __restrict__ w,
                            unsigned short* __restrict__ xb,
                            unsigned short* __restrict__ wb) {
    if (blockIdx.x < RED_BLOCKS) {
        const int total4 = SEQ * HID / 4;
        const float4* h4 = (const float4*)hs;
        ushort4* o4 = (ushort4*)xb;
        for (int i = blockIdx.x * blockDim.x + threadIdx.x; i < total4;
             i += RED_BLOCKS * blockDim.x) {
            float4 s = h4[i];
            #pragma unroll
            for (int ww = 1; ww < WORLD; ++ww) {
                float4 t = h4[i + ww * total4];
                s.x += t.x; s.y += t.y; s.z += t.z; s.w += t.w;
            }
            ushort4 o;
            o.x = f2bf(s.x); o.y = f2bf(s.y); o.z = f2bf(s.z); o.w = f2bf(s.w);
            o4[i] = o;
        }
    } else {
        const int total4 = OUTD * HID / 4;
        const float4* w4 = (const float4*)w;
        ushort4* o4 = (ushort4*)wb;
        for (int i = (blockIdx.x - RED_BLOCKS) * blockDim.x + threadIdx.x;
             i < total4; i += CONV_BLOCKS * blockDim.x) {
            float4 s = w4[i];
            ushort4 o;
            o.x = f2bf(s.x); o.y = f2bf(s.y); o.z = f2bf(s.z); o.w = f2bf(s.w);
            o4[i] = o;
        }
    }
}

// ------ Kernel 2: 256x256 bf16 GEMM C = A*B^T, NO-DRAIN single-barrier K-loop ------
// 8 waves (2Mx4N), 128x64 out/wave. LDS dbuf A/B [2][256][64] bf16 = 128 KiB.
// Swizzle: 16B slot' = slot ^ (row&7) on pre-swizzled global source + ds_read.
// Per K-tile t (buf p): ONE asm s_barrier (compiler memory fence), stage(t+1)->q,
// 24 ds_reads + 64 MFMA with ONLY the compiler's fine-grained counted lgkm waits
// (no lgkmcnt(0) drain, no sched_barrier pins), then vmcnt(0) (pro-forma: the 8
// stages had a full tile in flight).
// Safety by consumption-certifies-retirement:
//  - reads of buf q (tile t-1) are all consumed by t-1's MFMAs before barrier(t)
//    (program order + data deps force counted lgkm waits) => retired => stage->q
//    after barrier(t) cannot clobber un-read data. No workgroup LDS drain needed.
//  - reads of tile t are certified by vmcnt(0) at end of t-1 + barrier.
// Waves may skew inside the tile: early waves run MFMA while late waves' reads
// drain -- the read/MFMA overlap that the lgkmcnt(0) convoy (r4-r7) prevented.

#define BM 256
#define BN 256
#define BK 64
#define KSTEPS (HID / BK)   // 64

__global__ __launch_bounds__(512, 2)
void gemm_bt_kernel(const unsigned short* __restrict__ A,
                    const unsigned short* __restrict__ B,
                    float* __restrict__ C) {
    __shared__ __align__(16) unsigned short lsA[2][BM * BK];   // 64 KiB
    __shared__ __align__(16) unsigned short lsB[2][BN * BK];   // 64 KiB

    const int tid  = threadIdx.x;
    const int lane = tid & 63;
    const int wave = tid >> 6;
    const int wm   = wave >> 2;     // 0..1  -> rows wm*128
    const int wn   = wave & 3;      // 0..3  -> cols wn*64

    // 2D XCD tiling: xcd = bid&7 -> (gm,gn)=(xcd>>2, xcd&3); local 32 blocks = 4x8.
    const int bid   = blockIdx.x;
    const int xcd   = bid & 7;
    const int local = bid >> 3;               // 0..31
    const int bm = (xcd >> 2) * 4 + (local >> 3);   // 0..7
    const int bn = (xcd & 3) * 8 + (local & 7);     // 0..31

    // ---- staging geometry: lane -> (subrow = lane>>3, slot = lane&7) ----
    const int subrow = lane >> 3;
    const int slot   = lane & 7;
    const int scol   = (slot ^ subrow) * 8;   // pre-swizzled global col (elems)
    const unsigned short* aBase =
        A + (size_t)(bm * BM + wave * 8 + subrow) * HID + scol;
    const unsigned short* bBase =
        B + (size_t)(bn * BN + wave * 8 + subrow) * HID + scol;
    const int ldsW = wave * 8 * BK;           // wave-uniform LDS elem offset

#define ST_A(buf, ktv, l) __builtin_amdgcn_global_load_lds(                     \
        (gas1_ptr)(aBase + (size_t)(ktv) * BK + (size_t)(l) * 64 * HID),        \
        (las3_ptr)(&lsA[buf][(l) * 64 * BK + ldsW]), 16, 0, 0)
#define ST_B(buf, ktv, l) __builtin_amdgcn_global_load_lds(                     \
        (gas1_ptr)(bBase + (size_t)(ktv) * BK + (size_t)(l) * 64 * HID),        \
        (las3_ptr)(&lsB[buf][(l) * 64 * BK + ldsW]), 16, 0, 0)
#define STG_A4(buf, ktv) do { ST_A(buf, ktv, 0); ST_A(buf, ktv, 1);             \
                              ST_A(buf, ktv, 2); ST_A(buf, ktv, 3); } while (0)
#define STG_B4(buf, ktv) do { ST_B(buf, ktv, 0); ST_B(buf, ktv, 1);             \
                              ST_B(buf, ktv, 2); ST_B(buf, ktv, 3); } while (0)

    // ---- fragment geometry ----
    const int fr    = lane & 15;
    const int fq    = lane >> 4;
    const int axor  = fr & 7;                  // (row & 7) for fragment rows
    const int koff0 = ((0 + fq) ^ axor) * 8;   // k-slice s=0
    const int koff1 = ((4 + fq) ^ axor) * 8;   // k-slice s=1
    const int aRowB = (wm * 128 + fr) * BK;
    const int bRowB = (wn * 64 + fr) * BK;

#define RD_A(dst, P, mm, koff) dst = __builtin_bit_cast(bf16x8,                 \
        *(const s16x8*)&lsA[P][aRowB + (mm) * 16 * BK + (koff)])
#define RD_B(dst, P, nn, koff) dst = __builtin_bit_cast(bf16x8,                 \
        *(const s16x8*)&lsB[P][bRowB + (nn) * 16 * BK + (koff)])

// asm barrier: the HW barrier AND a compiler memory fence (ds ops cannot cross)
#define BARRIER_M() asm volatile("s_barrier" ::: "memory")
#define VMC0()      asm volatile("s_waitcnt vmcnt(0)" ::: "memory")
#define PRIO1()     __builtin_amdgcn_s_setprio(1)
#define PRIO0()     __builtin_amdgcn_s_setprio(0)

// 16-MFMA cluster: m-pair (mb, mb+1) x n0-3, both k-slices, from array VAx
#define MFMA16(VAx, mb)                                                          \
    PRIO1();                                                                     \
    _Pragma("unroll")                                                            \
    for (int s = 0; s < 2; ++s)                                                  \
        _Pragma("unroll")                                                        \
        for (int m = 0; m < 2; ++m)                                              \
            _Pragma("unroll")                                                    \
            for (int n = 0; n < 4; ++n)                                          \
                acc[(mb) + m][n] = __builtin_amdgcn_mfma_f32_16x16x32_bf16(      \
                    VAx[m][s], vb[n][s], acc[(mb) + m][n], 0, 0, 0);             \
    PRIO0()

// One K-tile on buffer P. HAS1: tile T+1 exists (stage it into P^1).
// No lgkm0, no sched_barrier: compiler interleaves reads/MFMA with counted waits.
#define TILE(P, T, HAS1)                                                         \
    BARRIER_M();                                                                 \
    if (HAS1) { STG_A4((P) ^ 1, (T) + 1); STG_B4((P) ^ 1, (T) + 1); }            \
    RD_B(vb[0][0], P, 0, koff0); RD_B(vb[0][1], P, 0, koff1);                    \
    RD_B(vb[1][0], P, 1, koff0); RD_B(vb[1][1], P, 1, koff1);                    \
    RD_B(vb[2][0], P, 2, koff0); RD_B(vb[2][1], P, 2, koff1);                    \
    RD_B(vb[3][0], P, 3, koff0); RD_B(vb[3][1], P, 3, koff1);                    \
    RD_A(va[0][0], P, 0, koff0); RD_A(va[0][1], P, 0, koff1);                    \
    RD_A(va[1][0], P, 1, koff0); RD_A(va[1][1], P, 1, koff1);                    \
    MFMA16(va, 0);                                                               \
    RD_A(vc[0][0], P, 2, koff0); RD_A(vc[0][1], P, 2, koff1);                    \
    RD_A(vc[1][0], P, 3, koff0); RD_A(vc[1][1], P, 3, koff1);                    \
    MFMA16(vc, 2);                                                               \
    RD_A(va[0][0], P, 4, koff0); RD_A(va[0][1], P, 4, koff1);                    \
    RD_A(va[1][0], P, 5, koff0); RD_A(va[1][1], P, 5, koff1);                    \
    MFMA16(va, 4);                                                               \
    RD_A(vc[0][0], P, 6, koff0); RD_A(vc[0][1], P, 6, koff1);                    \
    RD_A(vc[1][0], P, 7, koff0); RD_A(vc[1][1], P, 7, koff1);                    \
    MFMA16(vc, 6);                                                               \
    if (HAS1) { VMC0(); }   /* stages had ~full tile in flight: pro-forma */

    f32x4 acc[8][4] = {};
    bf16x8 va[2][2], vc[2][2], vb[4][2];

    // ---- prologue: stage tile0 -> buf0 (8 loads); certify ----
    STG_A4(0, 0); STG_B4(0, 0);
    VMC0();

    #pragma unroll 1
    for (int t = 0; t < KSTEPS; t += 2) {
        TILE(0, t,     true);                  // t+1 <= 63 always
        TILE(1, t + 1, (t + 2 < KSTEPS));
    }

    // ---- epilogue: C/D layout col = lane&15, row = (lane>>4)*4 + j ----
    const long crow0 = (long)bm * BM + wm * 128 + fq * 4;
    const long ccol0 = (long)bn * BN + wn * 64 + fr;
    #pragma unroll
    for (int m = 0; m < 8; ++m)
        #pragma unroll
        for (int n = 0; n < 4; ++n)
            #pragma unroll
            for (int j = 0; j < 4; ++j)
                C[(crow0 + m * 16 + j) * OUTD + ccol0 + n * 16] = acc[m][n][j];
}

extern "C" void kernel_launch(void* const* d_in, const int* in_sizes, int n_in,
                              void* d_out, int out_size, void* d_ws, size_t ws_size,
                              hipStream_t stream) {
    const float* hs = (const float*)d_in[0];
    const float* w  = (const float*)d_in[1];
    float* out = (float*)d_out;

    unsigned short* xb = (unsigned short*)d_ws;              // 16 MB  [SEQ][HID] bf16
    unsigned short* wb = xb + (size_t)SEQ * HID;             // 64 MB  [OUTD][HID] bf16

    hipLaunchKernelGGL(prep_kernel, dim3(RED_BLOCKS + CONV_BLOCKS), dim3(256),
                       0, stream, hs, w, xb, wb);
    hipLaunchKernelGGL(gemm_bt_kernel, dim3((SEQ / BM) * (OUTD / BN)), dim3(512),
                       0, stream, xb, wb, out);
}